// Round 19
// baseline (146.646 us; speedup 1.0000x reference)
//
#include <hip/hip_runtime.h>

#define NFULL 4096
#define CDIM  512
#define HEADS 8
#define DDIM  64

typedef unsigned short u16;
typedef short bf16x8 __attribute__((ext_vector_type(8)));
typedef float f32x4 __attribute__((ext_vector_type(4)));

#if __has_builtin(__builtin_amdgcn_exp2f)
__device__ __forceinline__ float exp2_hw(float x) { return __builtin_amdgcn_exp2f(x); }
#else
__device__ __forceinline__ float exp2_hw(float x) {
  float r;
  asm volatile("v_exp_f32 %0, %1\n\ts_nop 1" : "=v"(r) : "v"(x));
  return r;
}
#endif
#define EXP2(x) exp2_hw(x)

// q pre-scaled by SCALE * log2(e) so exp(s) == exp2(s').
#define QSCALE 11.541560327111707f  // 8 * 1.4426950408889634

__device__ __forceinline__ float dot4(float4 a, float4 b) {
  return a.x * b.x + a.y * b.y + a.z * b.z + a.w * b.w;
}

__device__ __forceinline__ u16 f2bf(float x) {  // RNE f32 -> bf16 bits
  union { float f; unsigned u; } v; v.f = x;
  unsigned r = v.u + 0x7fffu + ((v.u >> 16) & 1u);
  return (u16)(r >> 16);
}

__device__ __forceinline__ float bf2f(u16 b) {
  union { unsigned u; float f; } v; v.u = ((unsigned)b) << 16;
  return v.f;
}

// K0 (prep, ILP-restructured):
// blocks 0..31:  W_comp q rows b*16..+16 (K=32)
// blocks 32..95: W_comp kv rows 512+(b-32)*16..+16 (K=64)
// blocks 96..111: W_c, 4 rows x 256-k half each
// blocks 112..115: pw1bf; 116..119: pw2bf; 120: bias_c.
__global__ __launch_bounds__(256) void k_comp(const float* __restrict__ qw1,
                                              const float* __restrict__ kvw1,
                                              const float* __restrict__ qw2,
                                              const float* __restrict__ kvw2,
                                              const float* __restrict__ pww,
                                              const float* __restrict__ dww,
                                              const float* __restrict__ dwb,
                                              const float* __restrict__ pwb,
                                              const float* __restrict__ pw1,
                                              const float* __restrict__ pw2,
                                              u16* __restrict__ wcomp,
                                              u16* __restrict__ wcbf,
                                              u16* __restrict__ pw1bf,
                                              u16* __restrict__ pw2bf,
                                              float* __restrict__ bias_c) {
  const int tid = threadIdx.x;
  const int b = blockIdx.x;

  if (b < 96) {  // ---- W_comp composition, 16 rows/block, 32 accs/thread ----
    __shared__ float W2s[16][64];
    const bool isq = b < 32;
    const int r0 = isq ? b * 16 : 512 + (b - 32) * 16;
    const int K = isq ? 32 : 64;
    for (int u = tid; u < 16 * K; u += 256) {
      const int row = u / K, e = u - row * K;
      W2s[row][e] = isq ? qw2[(size_t)(r0 + row) * 32 + e]
                        : kvw2[(size_t)(r0 - 512 + row) * 64 + e];
    }
    __syncthreads();
    const float* __restrict__ w1 = isq ? qw1 : kvw1;
    float acc0[16], acc1[16];
#pragma unroll
    for (int r = 0; r < 16; ++r) { acc0[r] = 0.f; acc1[r] = 0.f; }
#pragma unroll 4
    for (int e = 0; e < 64; ++e) {
      if (e >= K) break;
      const float v0 = w1[(size_t)e * 512 + tid];
      const float v1 = w1[(size_t)e * 512 + tid + 256];
#pragma unroll
      for (int r = 0; r < 16; ++r) {
        const float w = W2s[r][e];
        acc0[r] += w * v0;
        acc1[r] += w * v1;
      }
    }
#pragma unroll
    for (int r = 0; r < 16; ++r) {
      wcomp[(size_t)(r0 + r) * 512 + tid] = f2bf(acc0[r]);
      wcomp[(size_t)(r0 + r) * 512 + tid + 256] = f2bf(acc1[r]);
    }
  } else if (b < 112) {  // ---- W_c: 4 rows x half-k, 4 accs/thread ----
    __shared__ float P1[4][512];
    const int b2 = b - 96;
    const int r0c = (b2 >> 1) * 4;
    const int k = (b2 & 1) * 256 + tid;
    for (int u = tid; u < 2048; u += 256)
      P1[u >> 9][u & 511] = pw1[(size_t)(r0c + (u >> 9)) * 512 + (u & 511)];
    __syncthreads();
    float a0 = 0.f, a1 = 0.f, a2 = 0.f, a3 = 0.f;
#pragma unroll 4
    for (int c = 0; c < 512; ++c) {
      const float pv = pww[(size_t)c * 512 + k];
      a0 += P1[0][c] * pv;
      a1 += P1[1][c] * pv;
      a2 += P1[2][c] * pv;
      a3 += P1[3][c] * pv;
    }
    const float d = dww[k];
    wcbf[(size_t)(r0c + 0) * 512 + k] = f2bf(a0 * d);
    wcbf[(size_t)(r0c + 1) * 512 + k] = f2bf(a1 * d);
    wcbf[(size_t)(r0c + 2) * 512 + k] = f2bf(a2 * d);
    wcbf[(size_t)(r0c + 3) * 512 + k] = f2bf(a3 * d);
  } else if (b < 120) {  // ---- pw1bf / pw2bf ----
    const float* src;
    u16* dst;
    int base;
    if (b < 116) { base = (b - 112) * 4096 + tid * 16; src = pw1; dst = pw1bf; }
    else         { base = (b - 116) * 4096 + tid * 16; src = pw2; dst = pw2bf; }
    u16 o[16];
#pragma unroll
    for (int q = 0; q < 4; ++q) {
      const float4 w = *(const float4*)&src[base + q * 4];
      o[q * 4 + 0] = f2bf(w.x); o[q * 4 + 1] = f2bf(w.y);
      o[q * 4 + 2] = f2bf(w.z); o[q * 4 + 3] = f2bf(w.w);
    }
    *(uint4*)&dst[base] = *(const uint4*)&o[0];
    *(uint4*)&dst[base + 8] = *(const uint4*)&o[8];
  } else {  // ---- bias_c: wave-per-row coalesced reductions ----
    __shared__ float dwbs[512];
    __shared__ float tmp[512];
    const int wave = tid >> 6, lane = tid & 63;
    for (int u = tid; u < 512; u += 256) dwbs[u] = dwb[u];
    __syncthreads();
    // phase 1: bias2 (incl pwb) -> tmp, 4 waves x 128 rows
    for (int c = wave * 128; c < wave * 128 + 128; ++c) {
      const float4 p0 = *(const float4*)&pww[(size_t)c * 512 + lane * 8];
      const float4 p1 = *(const float4*)&pww[(size_t)c * 512 + lane * 8 + 4];
      const float4 d0 = *(const float4*)&dwbs[lane * 8];
      const float4 d1 = *(const float4*)&dwbs[lane * 8 + 4];
      float part = dot4(p0, d0) + dot4(p1, d1);
      part += __shfl_xor(part, 1);
      part += __shfl_xor(part, 2);
      part += __shfl_xor(part, 4);
      part += __shfl_xor(part, 8);
      part += __shfl_xor(part, 16);
      part += __shfl_xor(part, 32);
      if (lane == 0) tmp[c] = part + pwb[c];
    }
    __syncthreads();
    // phase 2: bias_c[r] = dot(pw1[r,:], tmp), 4 waves x 8 rows
    for (int r = wave * 8; r < wave * 8 + 8; ++r) {
      const float4 p0 = *(const float4*)&pw1[(size_t)r * 512 + lane * 8];
      const float4 p1 = *(const float4*)&pw1[(size_t)r * 512 + lane * 8 + 4];
      const float4 t0 = *(const float4*)&tmp[lane * 8];
      const float4 t1 = *(const float4*)&tmp[lane * 8 + 4];
      float part = dot4(p0, t0) + dot4(p1, t1);
      part += __shfl_xor(part, 1);
      part += __shfl_xor(part, 2);
      part += __shfl_xor(part, 4);
      part += __shfl_xor(part, 8);
      part += __shfl_xor(part, 16);
      part += __shfl_xor(part, 32);
      if (lane == 0) bias_c[r] = part;
    }
  }
}

// K1: q/k/v = x @ W_comp^T, one GEMM. Grid 1536 = 64 row x 24 col blocks.
__global__ __launch_bounds__(256) void k_qkv(const float* __restrict__ x,
                                             const u16* __restrict__ wcomp,
                                             u16* __restrict__ qb,
                                             u16* __restrict__ kb,
                                             float* __restrict__ vh) {
  __shared__ __align__(16) u16 Ab[64][72];
  __shared__ __align__(16) u16 Wb[64][72];
  const int bc = blockIdx.x % 24;
  const int rb = blockIdx.x / 24;
  const int r0 = rb * 64, c0 = bc * 64;
  const int tid = threadIdx.x;
  const int wave = tid >> 6, lane = tid & 63;
  const int lrow = lane & 15, g = lane >> 4;
  const int srow = tid >> 2;
  const int skc = (tid & 3) * 16;

  f32x4 acc[4];
#pragma unroll
  for (int ct = 0; ct < 4; ++ct) acc[ct] = (f32x4){0.f, 0.f, 0.f, 0.f};

  const float* __restrict__ ap = x + (size_t)(r0 + srow) * 512 + skc;
  const u16* __restrict__ wp = wcomp + (size_t)(c0 + srow) * 512 + skc;
  float4 a4[4];
#pragma unroll
  for (int e = 0; e < 4; ++e) a4[e] = *(const float4*)(ap + e * 4);
  uint4 w0 = *(const uint4*)wp;
  uint4 w1 = *(const uint4*)(wp + 8);

  for (int k0 = 0; k0 < 512; k0 += 64) {
    u16 ab16[16];
#pragma unroll
    for (int e = 0; e < 4; ++e) {
      ab16[e * 4 + 0] = f2bf(a4[e].x);
      ab16[e * 4 + 1] = f2bf(a4[e].y);
      ab16[e * 4 + 2] = f2bf(a4[e].z);
      ab16[e * 4 + 3] = f2bf(a4[e].w);
    }
    __syncthreads();
    *(uint4*)&Ab[srow][skc] = *(const uint4*)&ab16[0];
    *(uint4*)&Ab[srow][skc + 8] = *(const uint4*)&ab16[8];
    *(uint4*)&Wb[srow][skc] = w0;
    *(uint4*)&Wb[srow][skc + 8] = w1;
    __syncthreads();
    if (k0 + 64 < 512) {
#pragma unroll
      for (int e = 0; e < 4; ++e) a4[e] = *(const float4*)(ap + k0 + 64 + e * 4);
      w0 = *(const uint4*)(wp + k0 + 64);
      w1 = *(const uint4*)(wp + k0 + 64 + 8);
    }
#pragma unroll
    for (int kk = 0; kk < 2; ++kk) {
      const bf16x8 af = *(const bf16x8*)&Ab[wave * 16 + lrow][kk * 32 + g * 8];
#pragma unroll
      for (int ct = 0; ct < 4; ++ct) {
        const bf16x8 wf = *(const bf16x8*)&Wb[ct * 16 + lrow][kk * 32 + g * 8];
        acc[ct] = __builtin_amdgcn_mfma_f32_16x16x32_bf16(wf, af, acc[ct], 0, 0, 0);
      }
    }
  }
  const int n = r0 + wave * 16 + lrow;
#pragma unroll
  for (int ct = 0; ct < 4; ++ct) {
    const int colg0 = c0 + ct * 16 + g * 4;
    if (bc < 8) {
      const int hh = colg0 >> 6, d0 = colg0 & 63;
      u16 o4[4] = {f2bf(acc[ct][0] * QSCALE), f2bf(acc[ct][1] * QSCALE),
                   f2bf(acc[ct][2] * QSCALE), f2bf(acc[ct][3] * QSCALE)};
      *(uint2*)&qb[((size_t)hh * NFULL + n) * 64 + d0] = *(const uint2*)o4;
    } else if (bc < 16) {
      const int c2 = colg0 - 512;
      const int hh = c2 >> 6, d0 = c2 & 63;
      u16 o4[4] = {f2bf(acc[ct][0]), f2bf(acc[ct][1]),
                   f2bf(acc[ct][2]), f2bf(acc[ct][3])};
      *(uint2*)&kb[((size_t)hh * NFULL + n) * 64 + d0] = *(const uint2*)o4;
    } else {
      const int c2 = colg0 - 1024;
      const int hh = c2 >> 6, d0 = c2 & 63;
      float4 o4;
      o4.x = acc[ct][0]; o4.y = acc[ct][1]; o4.z = acc[ct][2]; o4.w = acc[ct][3];
      *(float4*)&vh[((size_t)hh * NFULL + n) * 64 + d0] = o4;
    }
  }
}

// K2: attention (frozen structure). Block (h, qt, s): 128 queries, keys
// [s*2048,+2048) in 32 tiles; wave-private global_load_lds staging, 4-deep
// circular swizzled LDS buffer, counted vmcnt, no main-loop barriers.
__global__ __launch_bounds__(256, 2) void k_attn(const u16* __restrict__ qb,
                                                 const u16* __restrict__ kb,
                                                 const float* __restrict__ vh,
                                                 u16* __restrict__ wv16,
                                                 float* __restrict__ dsp) {
  __shared__ __align__(16) u16 KB[4][64][64];
  __shared__ float P_lds[8][16][17];
  __shared__ float Ds[4][8][16];

  const int h = blockIdx.x & 7;
  const int qt = (blockIdx.x >> 3) & 31;
  const int s = blockIdx.x >> 8;
  const int q0 = qt * 128;
  const int tid = threadIdx.x;
  const int wave = tid >> 6, lane = tid & 63;
  const int lrow = lane & 15, g = lane >> 4;

  const u16* __restrict__ Qg = qb + ((size_t)h * NFULL + q0) * 64;
  const u16* __restrict__ Kg = kb + ((size_t)h * NFULL + (size_t)s * 2048) * 64;

  bf16x8 qf[8][2];
#pragma unroll
  for (int j = 0; j < 8; ++j) {
    qf[j][0] = *(const bf16x8*)&Qg[(j * 16 + lrow) * 64 + g * 8];
    qf[j][1] = *(const bf16x8*)&Qg[(j * 16 + lrow) * 64 + 32 + g * 8];
  }

  const int srow8 = lane >> 3;
  const int scol = ((lane & 7) ^ srow8) << 3;

#define STAGE(T, B)                                                           \
  do {                                                                        \
    const u16* tb_ = Kg + (size_t)(T) * 64 * 64;                              \
    {                                                                         \
      const u16* src_ = tb_ + (wave * 16 + srow8) * 64 + scol;                \
      u16* dst_ = &KB[(B)][wave * 16][0];                                     \
      __builtin_amdgcn_global_load_lds(                                       \
          (const __attribute__((address_space(1))) unsigned*)src_,            \
          (__attribute__((address_space(3))) unsigned*)dst_, 16, 0, 0);       \
    }                                                                         \
    {                                                                         \
      const u16* src_ = tb_ + (wave * 16 + 8 + srow8) * 64 + scol;            \
      u16* dst_ = &KB[(B)][wave * 16][0] + 512;                               \
      __builtin_amdgcn_global_load_lds(                                       \
          (const __attribute__((address_space(1))) unsigned*)src_,            \
          (__attribute__((address_space(3))) unsigned*)dst_, 16, 0, 0);       \
    }                                                                         \
  } while (0)

  const int rsw = wave * 16 + lrow;
  const int x0 = (g ^ (lrow & 7)) * 8;
  const int x1 = ((g + 4) ^ (lrow & 7)) * 8;

  float dsum[8];
#pragma unroll
  for (int j = 0; j < 8; ++j) dsum[j] = 0.f;
  const bool dg = (s == (qt >> 4));
  const int ql = qt & 15;

  auto tile = [&](int t, int b) {
    const bf16x8 kf0 = *(const bf16x8*)&KB[b][rsw][x0];
    const bf16x8 kf1 = *(const bf16x8*)&KB[b][rsw][x1];
#pragma unroll
    for (int hs = 0; hs < 2; ++hs) {
      f32x4 a[4];
      __builtin_amdgcn_s_setprio(1);
#pragma unroll
      for (int f = 0; f < 4; ++f) {
        f32x4 t4 = {0.f, 0.f, 0.f, 0.f};
        t4 = __builtin_amdgcn_mfma_f32_16x16x32_bf16(kf0, qf[hs * 4 + f][0], t4, 0, 0, 0);
        t4 = __builtin_amdgcn_mfma_f32_16x16x32_bf16(kf1, qf[hs * 4 + f][1], t4, 0, 0, 0);
        a[f] = t4;
      }
      __builtin_amdgcn_s_setprio(0);
      const bool isd = dg && (t == ql * 2 + hs);
#pragma unroll
      for (int f = 0; f < 4; ++f) {
        const float e0 = EXP2(a[f][0]);
        const float e1 = EXP2(a[f][1]);
        const float e2 = EXP2(a[f][2]);
        const float e3 = EXP2(a[f][3]);
        dsum[hs * 4 + f] += (e0 + e1) + (e2 + e3);
        if (isd && f == wave) {
          const int rr = g * 4;
          const int J = hs * 4 + wave;
          P_lds[J][rr + 0][lrow] = (rr + 0 <= lrow) ? e0 : 0.f;
          P_lds[J][rr + 1][lrow] = (rr + 1 <= lrow) ? e1 : 0.f;
          P_lds[J][rr + 2][lrow] = (rr + 2 <= lrow) ? e2 : 0.f;
          P_lds[J][rr + 3][lrow] = (rr + 3 <= lrow) ? e3 : 0.f;
        }
      }
    }
  };

  STAGE(0, 0); STAGE(1, 1); STAGE(2, 2);

  for (int t = 0; t < 28; t += 2) {
    STAGE(t + 3, (t + 3) & 3);
    asm volatile("s_waitcnt vmcnt(6)" ::: "memory");
    tile(t, t & 3);
    STAGE(t + 4, (t + 4) & 3);
    asm volatile("s_waitcnt vmcnt(6)" ::: "memory");
    tile(t + 1, (t + 1) & 3);
  }
  STAGE(31, 3);
  asm volatile("s_waitcnt vmcnt(6)" ::: "memory");
  tile(28, 0);
  asm volatile("s_waitcnt vmcnt(4)" ::: "memory");
  tile(29, 1);
  asm volatile("s_waitcnt vmcnt(2)" ::: "memory");
  tile(30, 2);
  asm volatile("s_waitcnt vmcnt(0)" ::: "memory");
  tile(31, 3);
#undef STAGE

#pragma unroll
  for (int j = 0; j < 8; ++j) {
    dsum[j] += __shfl_xor(dsum[j], 16);
    dsum[j] += __shfl_xor(dsum[j], 32);
  }
  if (g == 0) {
#pragma unroll
    for (int j = 0; j < 8; ++j) Ds[wave][j][lrow] = dsum[j];
  }
  __syncthreads();

  if (tid < 128) {
    const int J2 = tid >> 4, r = tid & 15;
    const float den = Ds[0][J2][r] + Ds[1][J2][r] + Ds[2][J2][r] + Ds[3][J2][r];
    dsp[((size_t)s * HEADS + h) * NFULL + q0 + J2 * 16 + r] = den;
  }

  if (dg) {
#pragma unroll
    for (int m = 0; m < 2; ++m) {
      const int J = m * 4 + wave;
      const float* __restrict__ V =
          vh + ((size_t)h * NFULL + q0 + J * 16) * 64 + g * 16;
      float o[16];
#pragma unroll
      for (int dd = 0; dd < 16; ++dd) o[dd] = 0.f;
#pragma unroll
      for (int k = 0; k < 16; ++k) {
        const float p = P_lds[J][k][lrow];
        const float4 v0 = *(const float4*)&V[k * 64 + 0];
        const float4 v1 = *(const float4*)&V[k * 64 + 4];
        const float4 v2 = *(const float4*)&V[k * 64 + 8];
        const float4 v3 = *(const float4*)&V[k * 64 + 12];
        o[0] += p * v0.x;  o[1] += p * v0.y;  o[2] += p * v0.z;  o[3] += p * v0.w;
        o[4] += p * v1.x;  o[5] += p * v1.y;  o[6] += p * v1.z;  o[7] += p * v1.w;
        o[8] += p * v2.x;  o[9] += p * v2.y;  o[10] += p * v2.z; o[11] += p * v2.w;
        o[12] += p * v3.x; o[13] += p * v3.y; o[14] += p * v3.z; o[15] += p * v3.w;
      }
      u16 ob[16];
#pragma unroll
      for (int dd = 0; dd < 16; ++dd) ob[dd] = f2bf(o[dd]);
      u16* __restrict__ op =
          wv16 + (size_t)(q0 + J * 16 + lrow) * CDIM + h * 64 + g * 16;
      *(uint4*)&op[0] = *(const uint4*)&ob[0];
      *(uint4*)&op[8] = *(const uint4*)&ob[8];
    }
  }
}

// K3 (fused output): per 16-row block,
// tp[16][32] = norm(wv) @ W_c^T + x @ p_w1^T + bias_c ;  out = tp @ p_w2^T.
__global__ __launch_bounds__(256) void k_out(const u16* __restrict__ wv16,
                                             const float* __restrict__ x,
                                             const float* __restrict__ dsp,
                                             const u16* __restrict__ wcbf,
                                             const u16* __restrict__ pw1bf,
                                             const u16* __restrict__ pw2bf,
                                             const float* __restrict__ bias_c,
                                             float* __restrict__ out) {
  __shared__ __align__(16) u16 wvb[16][520];
  __shared__ __align__(16) u16 xb[16][520];
  __shared__ float tp_part[4][32][17];
  __shared__ float invs[16][8];
  const int r0 = blockIdx.x * 16;
  const int tid = threadIdx.x;
  const int wave = tid >> 6, lane = tid & 63;
  const int lrow = lane & 15, g = lane >> 4;

  if (tid < 128) {
    const int n = tid >> 3, hh = tid & 7;
    const size_t base = (size_t)hh * NFULL + r0 + n;
    invs[n][hh] = 1.0f / (dsp[base] + dsp[(size_t)8 * NFULL + base]);
  }
  __syncthreads();

  for (int rep = 0; rep < 4; ++rep) {
    const int idx = rep * 256 + tid;
    const int row = idx >> 6, c8 = (idx & 63) * 8;
    const float sc = invs[row][c8 >> 6];
    const uint4 wv8 = *(const uint4*)&wv16[(size_t)(r0 + row) * 512 + c8];
    const u16* pw = (const u16*)&wv8;
    u16 t8[8];
#pragma unroll
    for (int i = 0; i < 8; ++i) t8[i] = f2bf(bf2f(pw[i]) * sc);
    *(uint4*)&wvb[row][c8] = *(const uint4*)&t8[0];
    const float4 x0 = *(const float4*)&x[(size_t)(r0 + row) * 512 + c8];
    const float4 x1 = *(const float4*)&x[(size_t)(r0 + row) * 512 + c8 + 4];
    u16 u8[8] = {f2bf(x0.x), f2bf(x0.y), f2bf(x0.z), f2bf(x0.w),
                 f2bf(x1.x), f2bf(x1.y), f2bf(x1.z), f2bf(x1.w)};
    *(uint4*)&xb[row][c8] = *(const uint4*)&u8[0];
  }
  __syncthreads();

  {
    const bool isx = (wave & 2) != 0;
    const int kh = wave & 1;
    const u16* __restrict__ Wsrc = isx ? pw1bf : wcbf;
#pragma unroll
    for (int rt = 0; rt < 2; ++rt) {
      f32x4 acc = {0.f, 0.f, 0.f, 0.f};
#pragma unroll
      for (int ks = 0; ks < 8; ++ks) {
        const int K = kh * 256 + ks * 32 + g * 8;
        const bf16x8 aw = *(const bf16x8*)&Wsrc[(size_t)(rt * 16 + lrow) * 512 + K];
        const bf16x8 bf = isx ? *(const bf16x8*)&xb[lrow][K]
                              : *(const bf16x8*)&wvb[lrow][K];
        acc = __builtin_amdgcn_mfma_f32_16x16x32_bf16(aw, bf, acc, 0, 0, 0);
      }
#pragma unroll
      for (int j = 0; j < 4; ++j)
        tp_part[wave][rt * 16 + g * 4 + j][lrow] = acc[j];
    }
  }
  __syncthreads();

  union { u16 a[8]; bf16x8 v; } bq;
#pragma unroll
  for (int i = 0; i < 8; ++i) {
    const int k = g * 8 + i;
    bq.a[i] = f2bf(tp_part[0][k][lrow] + tp_part[1][k][lrow] +
                   tp_part[2][k][lrow] + tp_part[3][k][lrow] + bias_c[k]);
  }

#pragma unroll
  for (int t = 0; t < 8; ++t) {
    const int ct = wave * 8 + t;
    const bf16x8 aw = *(const bf16x8*)&pw2bf[(size_t)(ct * 16 + lrow) * 32 + g * 8];
    f32x4 acc = {0.f, 0.f, 0.f, 0.f};
    acc = __builtin_amdgcn_mfma_f32_16x16x32_bf16(aw, bq.v, acc, 0, 0, 0);
    float4 res;
    res.x = acc[0]; res.y = acc[1]; res.z = acc[2]; res.w = acc[3];
    *(float4*)&out[(size_t)(r0 + lrow) * 512 + ct * 16 + g * 4] = res;
  }
}

extern "C" void kernel_launch(void* const* d_in, const int* in_sizes, int n_in,
                              void* d_out, int out_size, void* d_ws, size_t ws_size,
                              hipStream_t stream) {
  const float* x     = (const float*)d_in[0];
  const float* q_w1  = (const float*)d_in[1];
  const float* q_w2  = (const float*)d_in[2];
  const float* kv_w1 = (const float*)d_in[3];
  const float* kv_w2 = (const float*)d_in[4];
  const float* dw_w  = (const float*)d_in[5];
  const float* dw_b  = (const float*)d_in[6];
  const float* pw_w  = (const float*)d_in[7];
  const float* pw_b  = (const float*)d_in[8];
  const float* p_w1  = (const float*)d_in[9];
  const float* p_w2  = (const float*)d_in[10];
  float* out = (float*)d_out;

  char* ws = (char*)d_ws;
  float* dsp    = (float*)ws;                        // 2*8*4096 f32 (256KB)
  float* bias_c = (float*)(ws + 262144);             // 32 f32 (pad 4KB)
  u16*   wcbf   = (u16*)(ws + 262144 + 4096);        // 32*512 u16 (32KB)
  u16*   pw1bf  = wcbf + 16384;                      // 32KB
  u16*   pw2bf  = pw1bf + 16384;                     // 32KB
  u16*   wcomp  = pw2bf + 16384;                     // 1536*512 u16 (1.5MB)
  u16*   qbw    = wcomp + (size_t)1536 * 512;        // 2M u16 (4MB)
  u16*   kbw    = qbw + (size_t)HEADS * NFULL * DDIM;  // 2M u16 (4MB)
  float* vh     = (float*)(kbw + (size_t)HEADS * NFULL * DDIM);  // 2M f32 (8MB)
  u16*   wv16   = (u16*)(vh + (size_t)HEADS * NFULL * DDIM);     // 2M u16 (4MB)

  k_comp<<<121, 256, 0, stream>>>(q_w1, kv_w1, q_w2, kv_w2, pw_w, dw_w, dw_b,
                                  pw_b, p_w1, p_w2, wcomp, wcbf, pw1bf, pw2bf,
                                  bias_c);
  k_qkv<<<1536, 256, 0, stream>>>(x, wcomp, qbw, kbw, vh);
  k_attn<<<2 * HEADS * (NFULL / 128), 256, 0, stream>>>(qbw, kbw, vh, wv16, dsp);
  k_out<<<NFULL / 16, 256, 0, stream>>>(wv16, x, dsp, wcbf, pw1bf, pw2bf, bias_c,
                                        out);
}

// Round 20
// 88.485 us; speedup vs baseline: 1.6573x; 1.6573x over previous
//
#include <hip/hip_runtime.h>

#define NFULL 4096
#define CDIM  512
#define HEADS 8
#define DDIM  64

typedef unsigned short u16;
typedef short bf16x8 __attribute__((ext_vector_type(8)));
typedef float f32x4 __attribute__((ext_vector_type(4)));

#if __has_builtin(__builtin_amdgcn_exp2f)
__device__ __forceinline__ float exp2_hw(float x) { return __builtin_amdgcn_exp2f(x); }
#else
__device__ __forceinline__ float exp2_hw(float x) {
  float r;
  asm volatile("v_exp_f32 %0, %1\n\ts_nop 1" : "=v"(r) : "v"(x));
  return r;
}
#endif
#define EXP2(x) exp2_hw(x)

// q pre-scaled by SCALE * log2(e) so exp(s) == exp2(s').
#define QSCALE 11.541560327111707f  // 8 * 1.4426950408889634

__device__ __forceinline__ float dot4(float4 a, float4 b) {
  return a.x * b.x + a.y * b.y + a.z * b.z + a.w * b.w;
}

__device__ __forceinline__ u16 f2bf(float x) {  // RNE f32 -> bf16 bits
  union { float f; unsigned u; } v; v.f = x;
  unsigned r = v.u + 0x7fffu + ((v.u >> 16) & 1u);
  return (u16)(r >> 16);
}

__device__ __forceinline__ float bf2f(u16 b) {
  union { unsigned u; float f; } v; v.u = ((unsigned)b) << 16;
  return v.f;
}

__device__ __forceinline__ float wave_red(float part) {
  part += __shfl_xor(part, 1);
  part += __shfl_xor(part, 2);
  part += __shfl_xor(part, 4);
  part += __shfl_xor(part, 8);
  part += __shfl_xor(part, 16);
  part += __shfl_xor(part, 32);
  return part;
}

// K0 (prep): 0..31 W_comp q rows (K=32); 32..95 W_comp kv rows (K=64);
// 96..111 W_c tiled mini-GEMM (32-col chunks); 112..127 bias2 (32 rows each);
// 128..131 pw1bf; 132..135 pw2bf.
__global__ __launch_bounds__(256) void k_comp(const float* __restrict__ qw1,
                                              const float* __restrict__ kvw1,
                                              const float* __restrict__ qw2,
                                              const float* __restrict__ kvw2,
                                              const float* __restrict__ pww,
                                              const float* __restrict__ dww,
                                              const float* __restrict__ dwb,
                                              const float* __restrict__ pwb,
                                              const float* __restrict__ pw1,
                                              const float* __restrict__ pw2,
                                              u16* __restrict__ wcomp,
                                              u16* __restrict__ wcbf,
                                              u16* __restrict__ pw1bf,
                                              u16* __restrict__ pw2bf,
                                              float* __restrict__ bias2) {
  const int tid = threadIdx.x;
  const int b = blockIdx.x;

  if (b < 96) {  // ---- W_comp composition, 16 rows/block, 32 accs/thread ----
    __shared__ float W2s[16][64];
    const bool isq = b < 32;
    const int r0 = isq ? b * 16 : 512 + (b - 32) * 16;
    if (isq) {
      for (int u = tid; u < 512; u += 256)
        W2s[u >> 5][u & 31] = qw2[(size_t)(r0 + (u >> 5)) * 32 + (u & 31)];
    } else {
      for (int u = tid; u < 1024; u += 256)
        W2s[u >> 6][u & 63] = kvw2[(size_t)(r0 - 512 + (u >> 6)) * 64 + (u & 63)];
    }
    __syncthreads();
    const float* __restrict__ w1 = isq ? qw1 : kvw1;
    float acc0[16], acc1[16];
#pragma unroll
    for (int r = 0; r < 16; ++r) { acc0[r] = 0.f; acc1[r] = 0.f; }
    if (isq) {
#pragma unroll 8
      for (int e = 0; e < 32; ++e) {
        const float v0 = w1[(size_t)e * 512 + tid];
        const float v1 = w1[(size_t)e * 512 + tid + 256];
#pragma unroll
        for (int r = 0; r < 16; ++r) {
          const float w = W2s[r][e];
          acc0[r] += w * v0;
          acc1[r] += w * v1;
        }
      }
    } else {
#pragma unroll 8
      for (int e = 0; e < 64; ++e) {
        const float v0 = w1[(size_t)e * 512 + tid];
        const float v1 = w1[(size_t)e * 512 + tid + 256];
#pragma unroll
        for (int r = 0; r < 16; ++r) {
          const float w = W2s[r][e];
          acc0[r] += w * v0;
          acc1[r] += w * v1;
        }
      }
    }
#pragma unroll
    for (int r = 0; r < 16; ++r) {
      wcomp[(size_t)(r0 + r) * 512 + tid] = f2bf(acc0[r]);
      wcomp[(size_t)(r0 + r) * 512 + tid + 256] = f2bf(acc1[r]);
    }
  } else if (b < 112) {  // ---- W_c tiled GEMM: 32-col chunk per block ----
    __shared__ __align__(16) float Pw[64][36];   // [c_local][k_local]
    __shared__ __align__(16) float P1s[32][68];  // [r][c_local]
    const int kc = (b - 96) * 32;
    const int r = tid >> 3;         // 0..31
    const int kl = (tid & 7) * 4;   // 0..28
    float a0 = 0.f, a1 = 0.f, a2 = 0.f, a3 = 0.f;
    for (int c0 = 0; c0 < 512; c0 += 64) {
      __syncthreads();
      for (int u = tid; u < 512; u += 256) {  // Pw: 64 rows x 32 cols (row-coalesced)
        const int row = u >> 3, cf = (u & 7) * 4;
        *(float4*)&Pw[row][cf] = *(const float4*)&pww[(size_t)(c0 + row) * 512 + kc + cf];
      }
      for (int u = tid; u < 512; u += 256) {  // P1s: 32 rows x 64 c
        const int row = u >> 4, cf = (u & 15) * 4;
        *(float4*)&P1s[row][cf] = *(const float4*)&pw1[(size_t)row * 512 + c0 + cf];
      }
      __syncthreads();
#pragma unroll 8
      for (int c = 0; c < 64; ++c) {
        const float av = P1s[r][c];
        const float4 pv = *(const float4*)&Pw[c][kl];
        a0 += av * pv.x; a1 += av * pv.y; a2 += av * pv.z; a3 += av * pv.w;
      }
    }
    const int k = kc + kl;
    const float4 d = *(const float4*)&dww[k];
    u16 o4[4] = {f2bf(a0 * d.x), f2bf(a1 * d.y), f2bf(a2 * d.z), f2bf(a3 * d.w)};
    *(uint2*)&wcbf[(size_t)r * 512 + k] = *(const uint2*)o4;
  } else if (b < 128) {  // ---- bias2: 32 rows/block, wave-per-row ----
    __shared__ float dwbs[512];
    for (int u = tid; u < 512; u += 256) dwbs[u] = dwb[u];
    __syncthreads();
    const int wave = tid >> 6, lane = tid & 63;
    const int rb2 = (b - 112) * 32 + wave * 8;
    for (int i = 0; i < 8; ++i) {
      const int c = rb2 + i;
      const float4 p0 = *(const float4*)&pww[(size_t)c * 512 + lane * 8];
      const float4 p1 = *(const float4*)&pww[(size_t)c * 512 + lane * 8 + 4];
      const float4 d0 = *(const float4*)&dwbs[lane * 8];
      const float4 d1 = *(const float4*)&dwbs[lane * 8 + 4];
      const float part = wave_red(dot4(p0, d0) + dot4(p1, d1));
      if (lane == 0) bias2[c] = part + pwb[c];
    }
  } else {  // ---- pw1bf / pw2bf ----
    const float* src;
    u16* dst;
    int base;
    if (b < 132) { base = (b - 128) * 4096 + tid * 16; src = pw1; dst = pw1bf; }
    else         { base = (b - 132) * 4096 + tid * 16; src = pw2; dst = pw2bf; }
    u16 o[16];
#pragma unroll
    for (int q = 0; q < 4; ++q) {
      const float4 w = *(const float4*)&src[base + q * 4];
      o[q * 4 + 0] = f2bf(w.x); o[q * 4 + 1] = f2bf(w.y);
      o[q * 4 + 2] = f2bf(w.z); o[q * 4 + 3] = f2bf(w.w);
    }
    *(uint4*)&dst[base] = *(const uint4*)&o[0];
    *(uint4*)&dst[base + 8] = *(const uint4*)&o[8];
  }
}

// K1: q/k/v = x @ W_comp^T, one GEMM. Blocks 0..1535; block 1536: bias_c.
__global__ __launch_bounds__(256) void k_qkv(const float* __restrict__ x,
                                             const u16* __restrict__ wcomp,
                                             const float* __restrict__ pw1,
                                             const float* __restrict__ bias2,
                                             u16* __restrict__ qb,
                                             u16* __restrict__ kb,
                                             float* __restrict__ vh,
                                             float* __restrict__ bias_c) {
  __shared__ __align__(16) u16 Ab[64][72];
  __shared__ __align__(16) u16 Wb[64][72];
  const int tid = threadIdx.x;

  if (blockIdx.x >= 1536) {  // bias_c[32] = pw1 @ bias2
    __shared__ float b2s[512];
    for (int u = tid; u < 512; u += 256) b2s[u] = bias2[u];
    __syncthreads();
    const int wave = tid >> 6, lane = tid & 63;
    for (int r = wave * 8; r < wave * 8 + 8; ++r) {
      const float4 p0 = *(const float4*)&pw1[(size_t)r * 512 + lane * 8];
      const float4 p1 = *(const float4*)&pw1[(size_t)r * 512 + lane * 8 + 4];
      const float4 t0 = *(const float4*)&b2s[lane * 8];
      const float4 t1 = *(const float4*)&b2s[lane * 8 + 4];
      const float part = wave_red(dot4(p0, t0) + dot4(p1, t1));
      if (lane == 0) bias_c[r] = part;
    }
    return;
  }

  const int bc = blockIdx.x % 24;
  const int rb = blockIdx.x / 24;
  const int r0 = rb * 64, c0 = bc * 64;
  const int wave = tid >> 6, lane = tid & 63;
  const int lrow = lane & 15, g = lane >> 4;
  const int srow = tid >> 2;
  const int skc = (tid & 3) * 16;

  f32x4 acc[4];
#pragma unroll
  for (int ct = 0; ct < 4; ++ct) acc[ct] = (f32x4){0.f, 0.f, 0.f, 0.f};

  const float* __restrict__ ap = x + (size_t)(r0 + srow) * 512 + skc;
  const u16* __restrict__ wp = wcomp + (size_t)(c0 + srow) * 512 + skc;
  float4 a4[4];
#pragma unroll
  for (int e = 0; e < 4; ++e) a4[e] = *(const float4*)(ap + e * 4);
  uint4 w0 = *(const uint4*)wp;
  uint4 w1 = *(const uint4*)(wp + 8);

  for (int k0 = 0; k0 < 512; k0 += 64) {
    u16 ab16[16];
#pragma unroll
    for (int e = 0; e < 4; ++e) {
      ab16[e * 4 + 0] = f2bf(a4[e].x);
      ab16[e * 4 + 1] = f2bf(a4[e].y);
      ab16[e * 4 + 2] = f2bf(a4[e].z);
      ab16[e * 4 + 3] = f2bf(a4[e].w);
    }
    __syncthreads();
    *(uint4*)&Ab[srow][skc] = *(const uint4*)&ab16[0];
    *(uint4*)&Ab[srow][skc + 8] = *(const uint4*)&ab16[8];
    *(uint4*)&Wb[srow][skc] = w0;
    *(uint4*)&Wb[srow][skc + 8] = w1;
    __syncthreads();
    if (k0 + 64 < 512) {
#pragma unroll
      for (int e = 0; e < 4; ++e) a4[e] = *(const float4*)(ap + k0 + 64 + e * 4);
      w0 = *(const uint4*)(wp + k0 + 64);
      w1 = *(const uint4*)(wp + k0 + 64 + 8);
    }
#pragma unroll
    for (int kk = 0; kk < 2; ++kk) {
      const bf16x8 af = *(const bf16x8*)&Ab[wave * 16 + lrow][kk * 32 + g * 8];
#pragma unroll
      for (int ct = 0; ct < 4; ++ct) {
        const bf16x8 wf = *(const bf16x8*)&Wb[ct * 16 + lrow][kk * 32 + g * 8];
        acc[ct] = __builtin_amdgcn_mfma_f32_16x16x32_bf16(wf, af, acc[ct], 0, 0, 0);
      }
    }
  }
  const int n = r0 + wave * 16 + lrow;
#pragma unroll
  for (int ct = 0; ct < 4; ++ct) {
    const int colg0 = c0 + ct * 16 + g * 4;
    if (bc < 8) {
      const int hh = colg0 >> 6, d0 = colg0 & 63;
      u16 o4[4] = {f2bf(acc[ct][0] * QSCALE), f2bf(acc[ct][1] * QSCALE),
                   f2bf(acc[ct][2] * QSCALE), f2bf(acc[ct][3] * QSCALE)};
      *(uint2*)&qb[((size_t)hh * NFULL + n) * 64 + d0] = *(const uint2*)o4;
    } else if (bc < 16) {
      const int c2 = colg0 - 512;
      const int hh = c2 >> 6, d0 = c2 & 63;
      u16 o4[4] = {f2bf(acc[ct][0]), f2bf(acc[ct][1]),
                   f2bf(acc[ct][2]), f2bf(acc[ct][3])};
      *(uint2*)&kb[((size_t)hh * NFULL + n) * 64 + d0] = *(const uint2*)o4;
    } else {
      const int c2 = colg0 - 1024;
      const int hh = c2 >> 6, d0 = c2 & 63;
      float4 o4;
      o4.x = acc[ct][0]; o4.y = acc[ct][1]; o4.z = acc[ct][2]; o4.w = acc[ct][3];
      *(float4*)&vh[((size_t)hh * NFULL + n) * 64 + d0] = o4;
    }
  }
}

// K2: attention (frozen structure). Block (h, qt, s): 128 queries, keys
// [s*2048,+2048) in 32 tiles; wave-private global_load_lds staging, 4-deep
// circular swizzled LDS buffer, counted vmcnt, no main-loop barriers.
__global__ __launch_bounds__(256, 2) void k_attn(const u16* __restrict__ qb,
                                                 const u16* __restrict__ kb,
                                                 const float* __restrict__ vh,
                                                 u16* __restrict__ wv16,
                                                 float* __restrict__ dsp) {
  __shared__ __align__(16) u16 KB[4][64][64];
  __shared__ float P_lds[8][16][17];
  __shared__ float Ds[4][8][16];

  const int h = blockIdx.x & 7;
  const int qt = (blockIdx.x >> 3) & 31;
  const int s = blockIdx.x >> 8;
  const int q0 = qt * 128;
  const int tid = threadIdx.x;
  const int wave = tid >> 6, lane = tid & 63;
  const int lrow = lane & 15, g = lane >> 4;

  const u16* __restrict__ Qg = qb + ((size_t)h * NFULL + q0) * 64;
  const u16* __restrict__ Kg = kb + ((size_t)h * NFULL + (size_t)s * 2048) * 64;

  bf16x8 qf[8][2];
#pragma unroll
  for (int j = 0; j < 8; ++j) {
    qf[j][0] = *(const bf16x8*)&Qg[(j * 16 + lrow) * 64 + g * 8];
    qf[j][1] = *(const bf16x8*)&Qg[(j * 16 + lrow) * 64 + 32 + g * 8];
  }

  const int srow8 = lane >> 3;
  const int scol = ((lane & 7) ^ srow8) << 3;

#define STAGE(T, B)                                                           \
  do {                                                                        \
    const u16* tb_ = Kg + (size_t)(T) * 64 * 64;                              \
    {                                                                         \
      const u16* src_ = tb_ + (wave * 16 + srow8) * 64 + scol;                \
      u16* dst_ = &KB[(B)][wave * 16][0];                                     \
      __builtin_amdgcn_global_load_lds(                                       \
          (const __attribute__((address_space(1))) unsigned*)src_,            \
          (__attribute__((address_space(3))) unsigned*)dst_, 16, 0, 0);       \
    }                                                                         \
    {                                                                         \
      const u16* src_ = tb_ + (wave * 16 + 8 + srow8) * 64 + scol;            \
      u16* dst_ = &KB[(B)][wave * 16][0] + 512;                               \
      __builtin_amdgcn_global_load_lds(                                       \
          (const __attribute__((address_space(1))) unsigned*)src_,            \
          (__attribute__((address_space(3))) unsigned*)dst_, 16, 0, 0);       \
    }                                                                         \
  } while (0)

  const int rsw = wave * 16 + lrow;
  const int x0 = (g ^ (lrow & 7)) * 8;
  const int x1 = ((g + 4) ^ (lrow & 7)) * 8;

  float dsum[8];
#pragma unroll
  for (int j = 0; j < 8; ++j) dsum[j] = 0.f;
  const bool dg = (s == (qt >> 4));
  const int ql = qt & 15;

  auto tile = [&](int t, int b) {
    const bf16x8 kf0 = *(const bf16x8*)&KB[b][rsw][x0];
    const bf16x8 kf1 = *(const bf16x8*)&KB[b][rsw][x1];
#pragma unroll
    for (int hs = 0; hs < 2; ++hs) {
      f32x4 a[4];
      __builtin_amdgcn_s_setprio(1);
#pragma unroll
      for (int f = 0; f < 4; ++f) {
        f32x4 t4 = {0.f, 0.f, 0.f, 0.f};
        t4 = __builtin_amdgcn_mfma_f32_16x16x32_bf16(kf0, qf[hs * 4 + f][0], t4, 0, 0, 0);
        t4 = __builtin_amdgcn_mfma_f32_16x16x32_bf16(kf1, qf[hs * 4 + f][1], t4, 0, 0, 0);
        a[f] = t4;
      }
      __builtin_amdgcn_s_setprio(0);
      const bool isd = dg && (t == ql * 2 + hs);
#pragma unroll
      for (int f = 0; f < 4; ++f) {
        const float e0 = EXP2(a[f][0]);
        const float e1 = EXP2(a[f][1]);
        const float e2 = EXP2(a[f][2]);
        const float e3 = EXP2(a[f][3]);
        dsum[hs * 4 + f] += (e0 + e1) + (e2 + e3);
        if (isd && f == wave) {
          const int rr = g * 4;
          const int J = hs * 4 + wave;
          P_lds[J][rr + 0][lrow] = (rr + 0 <= lrow) ? e0 : 0.f;
          P_lds[J][rr + 1][lrow] = (rr + 1 <= lrow) ? e1 : 0.f;
          P_lds[J][rr + 2][lrow] = (rr + 2 <= lrow) ? e2 : 0.f;
          P_lds[J][rr + 3][lrow] = (rr + 3 <= lrow) ? e3 : 0.f;
        }
      }
    }
  };

  STAGE(0, 0); STAGE(1, 1); STAGE(2, 2);

  for (int t = 0; t < 28; t += 2) {
    STAGE(t + 3, (t + 3) & 3);
    asm volatile("s_waitcnt vmcnt(6)" ::: "memory");
    tile(t, t & 3);
    STAGE(t + 4, (t + 4) & 3);
    asm volatile("s_waitcnt vmcnt(6)" ::: "memory");
    tile(t + 1, (t + 1) & 3);
  }
  STAGE(31, 3);
  asm volatile("s_waitcnt vmcnt(6)" ::: "memory");
  tile(28, 0);
  asm volatile("s_waitcnt vmcnt(4)" ::: "memory");
  tile(29, 1);
  asm volatile("s_waitcnt vmcnt(2)" ::: "memory");
  tile(30, 2);
  asm volatile("s_waitcnt vmcnt(0)" ::: "memory");
  tile(31, 3);
#undef STAGE

#pragma unroll
  for (int j = 0; j < 8; ++j) {
    dsum[j] += __shfl_xor(dsum[j], 16);
    dsum[j] += __shfl_xor(dsum[j], 32);
  }
  if (g == 0) {
#pragma unroll
    for (int j = 0; j < 8; ++j) Ds[wave][j][lrow] = dsum[j];
  }
  __syncthreads();

  if (tid < 128) {
    const int J2 = tid >> 4, r = tid & 15;
    const float den = Ds[0][J2][r] + Ds[1][J2][r] + Ds[2][J2][r] + Ds[3][J2][r];
    dsp[((size_t)s * HEADS + h) * NFULL + q0 + J2 * 16 + r] = den;
  }

  if (dg) {
#pragma unroll
    for (int m = 0; m < 2; ++m) {
      const int J = m * 4 + wave;
      const float* __restrict__ V =
          vh + ((size_t)h * NFULL + q0 + J * 16) * 64 + g * 16;
      float o[16];
#pragma unroll
      for (int dd = 0; dd < 16; ++dd) o[dd] = 0.f;
#pragma unroll
      for (int k = 0; k < 16; ++k) {
        const float p = P_lds[J][k][lrow];
        const float4 v0 = *(const float4*)&V[k * 64 + 0];
        const float4 v1 = *(const float4*)&V[k * 64 + 4];
        const float4 v2 = *(const float4*)&V[k * 64 + 8];
        const float4 v3 = *(const float4*)&V[k * 64 + 12];
        o[0] += p * v0.x;  o[1] += p * v0.y;  o[2] += p * v0.z;  o[3] += p * v0.w;
        o[4] += p * v1.x;  o[5] += p * v1.y;  o[6] += p * v1.z;  o[7] += p * v1.w;
        o[8] += p * v2.x;  o[9] += p * v2.y;  o[10] += p * v2.z; o[11] += p * v2.w;
        o[12] += p * v3.x; o[13] += p * v3.y; o[14] += p * v3.z; o[15] += p * v3.w;
      }
      u16 ob[16];
#pragma unroll
      for (int dd = 0; dd < 16; ++dd) ob[dd] = f2bf(o[dd]);
      u16* __restrict__ op =
          wv16 + (size_t)(q0 + J * 16 + lrow) * CDIM + h * 64 + g * 16;
      *(uint4*)&op[0] = *(const uint4*)&ob[0];
      *(uint4*)&op[8] = *(const uint4*)&ob[8];
    }
  }
}

// K3 (fused output): per 16-row block,
// tp[16][32] = norm(wv) @ W_c^T + x @ p_w1^T + bias_c ;  out = tp @ p_w2^T.
__global__ __launch_bounds__(256) void k_out(const u16* __restrict__ wv16,
                                             const float* __restrict__ x,
                                             const float* __restrict__ dsp,
                                             const u16* __restrict__ wcbf,
                                             const u16* __restrict__ pw1bf,
                                             const u16* __restrict__ pw2bf,
                                             const float* __restrict__ bias_c,
                                             float* __restrict__ out) {
  __shared__ __align__(16) u16 wvb[16][520];
  __shared__ __align__(16) u16 xb[16][520];
  __shared__ float tp_part[4][32][17];
  __shared__ float invs[16][8];
  const int r0 = blockIdx.x * 16;
  const int tid = threadIdx.x;
  const int wave = tid >> 6, lane = tid & 63;
  const int lrow = lane & 15, g = lane >> 4;

  if (tid < 128) {
    const int n = tid >> 3, hh = tid & 7;
    const size_t base = (size_t)hh * NFULL + r0 + n;
    invs[n][hh] = 1.0f / (dsp[base] + dsp[(size_t)8 * NFULL + base]);
  }
  __syncthreads();

  for (int rep = 0; rep < 4; ++rep) {
    const int idx = rep * 256 + tid;
    const int row = idx >> 6, c8 = (idx & 63) * 8;
    const float sc = invs[row][c8 >> 6];
    const uint4 wv8 = *(const uint4*)&wv16[(size_t)(r0 + row) * 512 + c8];
    const u16* pw = (const u16*)&wv8;
    u16 t8[8];
#pragma unroll
    for (int i = 0; i < 8; ++i) t8[i] = f2bf(bf2f(pw[i]) * sc);
    *(uint4*)&wvb[row][c8] = *(const uint4*)&t8[0];
    const float4 x0 = *(const float4*)&x[(size_t)(r0 + row) * 512 + c8];
    const float4 x1 = *(const float4*)&x[(size_t)(r0 + row) * 512 + c8 + 4];
    u16 u8[8] = {f2bf(x0.x), f2bf(x0.y), f2bf(x0.z), f2bf(x0.w),
                 f2bf(x1.x), f2bf(x1.y), f2bf(x1.z), f2bf(x1.w)};
    *(uint4*)&xb[row][c8] = *(const uint4*)&u8[0];
  }
  __syncthreads();

  {
    const bool isx = (wave & 2) != 0;
    const int kh = wave & 1;
    const u16* __restrict__ Wsrc = isx ? pw1bf : wcbf;
#pragma unroll
    for (int rt = 0; rt < 2; ++rt) {
      f32x4 acc = {0.f, 0.f, 0.f, 0.f};
#pragma unroll
      for (int ks = 0; ks < 8; ++ks) {
        const int K = kh * 256 + ks * 32 + g * 8;
        const bf16x8 aw = *(const bf16x8*)&Wsrc[(size_t)(rt * 16 + lrow) * 512 + K];
        const bf16x8 bf = isx ? *(const bf16x8*)&xb[lrow][K]
                              : *(const bf16x8*)&wvb[lrow][K];
        acc = __builtin_amdgcn_mfma_f32_16x16x32_bf16(aw, bf, acc, 0, 0, 0);
      }
#pragma unroll
      for (int j = 0; j < 4; ++j)
        tp_part[wave][rt * 16 + g * 4 + j][lrow] = acc[j];
    }
  }
  __syncthreads();

  union { u16 a[8]; bf16x8 v; } bq;
#pragma unroll
  for (int i = 0; i < 8; ++i) {
    const int k = g * 8 + i;
    bq.a[i] = f2bf(tp_part[0][k][lrow] + tp_part[1][k][lrow] +
                   tp_part[2][k][lrow] + tp_part[3][k][lrow] + bias_c[k]);
  }

#pragma unroll
  for (int t = 0; t < 8; ++t) {
    const int ct = wave * 8 + t;
    const bf16x8 aw = *(const bf16x8*)&pw2bf[(size_t)(ct * 16 + lrow) * 32 + g * 8];
    f32x4 acc = {0.f, 0.f, 0.f, 0.f};
    acc = __builtin_amdgcn_mfma_f32_16x16x32_bf16(aw, bq.v, acc, 0, 0, 0);
    float4 res;
    res.x = acc[0]; res.y = acc[1]; res.z = acc[2]; res.w = acc[3];
    *(float4*)&out[(size_t)(r0 + lrow) * 512 + ct * 16 + g * 4] = res;
  }
}

extern "C" void kernel_launch(void* const* d_in, const int* in_sizes, int n_in,
                              void* d_out, int out_size, void* d_ws, size_t ws_size,
                              hipStream_t stream) {
  const float* x     = (const float*)d_in[0];
  const float* q_w1  = (const float*)d_in[1];
  const float* q_w2  = (const float*)d_in[2];
  const float* kv_w1 = (const float*)d_in[3];
  const float* kv_w2 = (const float*)d_in[4];
  const float* dw_w  = (const float*)d_in[5];
  const float* dw_b  = (const float*)d_in[6];
  const float* pw_w  = (const float*)d_in[7];
  const float* pw_b  = (const float*)d_in[8];
  const float* p_w1  = (const float*)d_in[9];
  const float* p_w2  = (const float*)d_in[10];
  float* out = (float*)d_out;

  char* ws = (char*)d_ws;
  float* dsp    = (float*)ws;                        // 2*8*4096 f32 (256KB)
  float* bias2  = (float*)(ws + 262144);             // 512 f32
  float* bias_c = bias2 + 512;                       // 32 f32 (pad to 4KB)
  u16*   wcbf   = (u16*)(ws + 262144 + 4096);        // 32*512 u16 (32KB)
  u16*   pw1bf  = wcbf + 16384;                      // 32KB
  u16*   pw2bf  = pw1bf + 16384;                     // 32KB
  u16*   wcomp  = pw2bf + 16384;                     // 1536*512 u16 (1.5MB)
  u16*   qbw    = wcomp + (size_t)1536 * 512;        // 2M u16 (4MB)
  u16*   kbw    = qbw + (size_t)HEADS * NFULL * DDIM;  // 2M u16 (4MB)
  float* vh     = (float*)(kbw + (size_t)HEADS * NFULL * DDIM);  // 2M f32 (8MB)
  u16*   wv16   = (u16*)(vh + (size_t)HEADS * NFULL * DDIM);     // 2M u16 (4MB)

  k_comp<<<136, 256, 0, stream>>>(q_w1, kv_w1, q_w2, kv_w2, pw_w, dw_w, dw_b,
                                  pw_b, p_w1, p_w2, wcomp, wcbf, pw1bf, pw2bf,
                                  bias2);
  k_qkv<<<1537, 256, 0, stream>>>(x, wcomp, p_w1, bias2, qbw, kbw, vh, bias_c);
  k_attn<<<2 * HEADS * (NFULL / 128), 256, 0, stream>>>(qbw, kbw, vh, wv16, dsp);
  k_out<<<NFULL / 16, 256, 0, stream>>>(wv16, x, dsp, wcbf, pw1bf, pw2bf, bias_c,
                                        out);
}

// Round 21
// 75.347 us; speedup vs baseline: 1.9463x; 1.1744x over previous
//
#include <hip/hip_runtime.h>

#define NFULL 4096
#define CDIM  512
#define HEADS 8
#define DDIM  64

typedef unsigned short u16;
typedef short bf16x8 __attribute__((ext_vector_type(8)));
typedef float f32x4 __attribute__((ext_vector_type(4)));

#if __has_builtin(__builtin_amdgcn_exp2f)
__device__ __forceinline__ float exp2_hw(float x) { return __builtin_amdgcn_exp2f(x); }
#else
__device__ __forceinline__ float exp2_hw(float x) {
  float r;
  asm volatile("v_exp_f32 %0, %1\n\ts_nop 1" : "=v"(r) : "v"(x));
  return r;
}
#endif
#define EXP2(x) exp2_hw(x)

// q pre-scaled by SCALE * log2(e) so exp(s) == exp2(s').
#define QSCALE 11.541560327111707f  // 8 * 1.4426950408889634

__device__ __forceinline__ float dot4(float4 a, float4 b) {
  return a.x * b.x + a.y * b.y + a.z * b.z + a.w * b.w;
}

__device__ __forceinline__ u16 f2bf(float x) {  // RNE f32 -> bf16 bits
  union { float f; unsigned u; } v; v.f = x;
  unsigned r = v.u + 0x7fffu + ((v.u >> 16) & 1u);
  return (u16)(r >> 16);
}

__device__ __forceinline__ float bf2f(u16 b) {
  union { unsigned u; float f; } v; v.u = ((unsigned)b) << 16;
  return v.f;
}

// K1: blocks 0..127: t_bf[32 rows][96] = bf16(x @ [q_w1;kv_w1]^T), MFMA.
// 128..129: bias2 = dw_b@pw_w^T + pw_b.
// 130..193: W_c[r][k] = bf16( dww[k] * sum_c pw1[r][c]*pww[c][k] )
// 194..197: pw1bf = bf16(p_w1). 198..201: pw2bf = bf16(p_w2).
__global__ __launch_bounds__(256) void k_pre(const float* __restrict__ x,
                                             const float* __restrict__ qw1,
                                             const float* __restrict__ kvw1,
                                             u16* __restrict__ t_bf,
                                             const float* __restrict__ pww,
                                             const float* __restrict__ dww,
                                             const float* __restrict__ dwb,
                                             const float* __restrict__ pwb,
                                             const float* __restrict__ pw1,
                                             const float* __restrict__ pw2,
                                             float* __restrict__ bias2,
                                             u16* __restrict__ wcbf,
                                             u16* __restrict__ pw1bf,
                                             u16* __restrict__ pw2bf) {
  __shared__ __align__(16) u16 Xs[32][72];
  __shared__ __align__(16) u16 Ws[96][72];
  const int tid = threadIdx.x;

  if (blockIdx.x >= 128) {  // prep work
    const int b = blockIdx.x - 128;
    if (b < 2) {
      const int c = b * 256 + tid;
      float acc = 0.f;
      for (int e = 0; e < 512; e += 4)
        acc += dot4(*(const float4*)&pww[(size_t)c * 512 + e], *(const float4*)&dwb[e]);
      bias2[c] = acc + pwb[c];
    } else if (b < 66) {  // W_c: composed low-rank x pointwise weight
      const int b2 = b - 2;
      const int r = b2 >> 1;
      const int k = (b2 & 1) * 256 + tid;
      float acc = 0.f;
      for (int c = 0; c < 512; c += 4) {
        const float4 p = *(const float4*)&pw1[(size_t)r * 512 + c];
        acc += p.x * pww[(size_t)(c + 0) * 512 + k];
        acc += p.y * pww[(size_t)(c + 1) * 512 + k];
        acc += p.z * pww[(size_t)(c + 2) * 512 + k];
        acc += p.w * pww[(size_t)(c + 3) * 512 + k];
      }
      wcbf[(size_t)r * 512 + k] = f2bf(acc * dww[k]);
    } else {
      const float* src;
      u16* dst;
      int base;
      if (b < 70) { base = (b - 66) * 4096 + tid * 16; src = pw1; dst = pw1bf; }
      else        { base = (b - 70) * 4096 + tid * 16; src = pw2; dst = pw2bf; }
      u16 o[16];
#pragma unroll
      for (int q = 0; q < 4; ++q) {
        const float4 w = *(const float4*)&src[base + q * 4];
        o[q * 4 + 0] = f2bf(w.x); o[q * 4 + 1] = f2bf(w.y);
        o[q * 4 + 2] = f2bf(w.z); o[q * 4 + 3] = f2bf(w.w);
      }
      *(uint4*)&dst[base] = *(const uint4*)&o[0];
      *(uint4*)&dst[base + 8] = *(const uint4*)&o[8];
    }
    return;
  }

  const int r0 = blockIdx.x * 32;
  const int wave = tid >> 6, lane = tid & 63;
  const int lrow = lane & 15, g = lane >> 4;
  const int rs = wave >> 1, ws2 = wave & 1;

  f32x4 acc[3];
#pragma unroll
  for (int sub = 0; sub < 3; ++sub) acc[sub] = (f32x4){0.f, 0.f, 0.f, 0.f};

  for (int k0 = 0; k0 < 512; k0 += 64) {
    __syncthreads();
    {
      const int row = tid >> 3, c16 = (tid & 7) * 8;
      const float* __restrict__ src = x + (size_t)(r0 + row) * 512 + k0 + c16;
      const float4 v0 = *(const float4*)(src);
      const float4 v1 = *(const float4*)(src + 4);
      u16 tmp[8] = {f2bf(v0.x), f2bf(v0.y), f2bf(v0.z), f2bf(v0.w),
                    f2bf(v1.x), f2bf(v1.y), f2bf(v1.z), f2bf(v1.w)};
      *(uint4*)&Xs[row][c16] = *(const uint4*)&tmp[0];
    }
    for (int u = tid; u < 768; u += 256) {
      const int c = u >> 3, c16 = (u & 7) * 8;
      const float* __restrict__ src =
          (c < 32 ? qw1 + (size_t)c * 512 : kvw1 + (size_t)(c - 32) * 512) + k0 + c16;
      const float4 v0 = *(const float4*)(src);
      const float4 v1 = *(const float4*)(src + 4);
      u16 tmp[8] = {f2bf(v0.x), f2bf(v0.y), f2bf(v0.z), f2bf(v0.w),
                    f2bf(v1.x), f2bf(v1.y), f2bf(v1.z), f2bf(v1.w)};
      *(uint4*)&Ws[c][c16] = *(const uint4*)&tmp[0];
    }
    __syncthreads();
    const bf16x8 a0 = *(const bf16x8*)&Xs[rs * 16 + lrow][g * 8];
    const bf16x8 a1 = *(const bf16x8*)&Xs[rs * 16 + lrow][32 + g * 8];
#pragma unroll
    for (int sub = 0; sub < 3; ++sub) {
      const int c = (ws2 * 3 + sub) * 16 + lrow;
      const bf16x8 b0 = *(const bf16x8*)&Ws[c][g * 8];
      const bf16x8 b1 = *(const bf16x8*)&Ws[c][32 + g * 8];
      acc[sub] = __builtin_amdgcn_mfma_f32_16x16x32_bf16(b0, a0, acc[sub], 0, 0, 0);
      acc[sub] = __builtin_amdgcn_mfma_f32_16x16x32_bf16(b1, a1, acc[sub], 0, 0, 0);
    }
  }
  const int n = r0 + rs * 16 + lrow;
#pragma unroll
  for (int sub = 0; sub < 3; ++sub) {
    u16 o4[4] = {f2bf(acc[sub][0]), f2bf(acc[sub][1]),
                 f2bf(acc[sub][2]), f2bf(acc[sub][3])};
    *(uint2*)&t_bf[(size_t)n * 96 + (ws2 * 3 + sub) * 16 + g * 4] = *(const uint2*)o4;
  }
}

// K2: q/k/v projections (blocks 0..767). Block 768: bias_c = bias2 @ p_w1^T.
__global__ __launch_bounds__(256) void k_proj2(const u16* __restrict__ t_bf,
                                               const float* __restrict__ qw2,
                                               const float* __restrict__ kvw2,
                                               const float* __restrict__ pw1,
                                               const float* __restrict__ bias2,
                                               u16* __restrict__ qb,
                                               u16* __restrict__ kb,
                                               float* __restrict__ vh,
                                               float* __restrict__ bias_c) {
  __shared__ __align__(16) u16 Ts[64][72];
  __shared__ __align__(16) u16 Wsh[128][72];
  __shared__ float red[8][32];
  const int tid = threadIdx.x;

  if (blockIdx.x >= 768) {  // bias_c[32]
    const int r = tid & 31, part = tid >> 5;  // 8 parts x 64 c
    float acc = 0.f;
    for (int c = part * 64; c < part * 64 + 64; ++c)
      acc += bias2[c] * pw1[(size_t)r * 512 + c];
    red[part][r] = acc;
    __syncthreads();
    if (tid < 32) {
      float s = 0.f;
#pragma unroll
      for (int p = 0; p < 8; ++p) s += red[p][tid];
      bias_c[tid] = s;
    }
    return;
  }

  const int cb = blockIdx.x % 12;
  const int r0 = (blockIdx.x / 12) * 64;
  const int wave = tid >> 6, lane = tid & 63;
  const int lrow = lane & 15, g = lane >> 4;
  const bool isq = cb < 4;
  const int c0 = isq ? cb * 128 : 512 + (cb - 4) * 128;

  for (int u = tid; u < 512; u += 256) {
    const int row = u >> 3, ch = (u & 7) * 8;
    uint4 v = {0u, 0u, 0u, 0u};
    if (isq) {
      if (ch < 32) v = *(const uint4*)&t_bf[(size_t)(r0 + row) * 96 + ch];
    } else {
      v = *(const uint4*)&t_bf[(size_t)(r0 + row) * 96 + 32 + ch];
    }
    *(uint4*)&Ts[row][ch] = v;
  }
  if (isq) {
    for (int u = tid; u < 1024; u += 256) {
      const int col = u >> 3, cf = (u & 7) * 4;
      const float4 v = *(const float4*)&qw2[(size_t)(c0 + col) * 32 + cf];
      u16 tmp[4] = {f2bf(v.x), f2bf(v.y), f2bf(v.z), f2bf(v.w)};
      *(uint2*)&Wsh[col][cf] = *(const uint2*)&tmp[0];
    }
  } else {
    for (int u = tid; u < 2048; u += 256) {
      const int col = u >> 4, cf = (u & 15) * 4;
      const float4 v = *(const float4*)&kvw2[(size_t)(c0 - 512 + col) * 64 + cf];
      u16 tmp[4] = {f2bf(v.x), f2bf(v.y), f2bf(v.z), f2bf(v.w)};
      *(uint2*)&Wsh[col][cf] = *(const uint2*)&tmp[0];
    }
  }
  __syncthreads();

  const int n = r0 + wave * 16 + lrow;
  if (isq) {
    const bf16x8 aq = *(const bf16x8*)&Ts[wave * 16 + lrow][g * 8];
#pragma unroll
    for (int sub = 0; sub < 8; ++sub) {
      const bf16x8 b0 = *(const bf16x8*)&Wsh[sub * 16 + lrow][g * 8];
      f32x4 acc = {0.f, 0.f, 0.f, 0.f};
      acc = __builtin_amdgcn_mfma_f32_16x16x32_bf16(b0, aq, acc, 0, 0, 0);
      const int colg0 = c0 + sub * 16 + g * 4;
      const int hh = colg0 >> 6, d0 = colg0 & 63;
      u16 o4[4] = {f2bf(acc[0] * QSCALE), f2bf(acc[1] * QSCALE),
                   f2bf(acc[2] * QSCALE), f2bf(acc[3] * QSCALE)};
      *(uint2*)&qb[((size_t)hh * NFULL + n) * 64 + d0] = *(const uint2*)o4;
    }
  } else {
    const bf16x8 a0 = *(const bf16x8*)&Ts[wave * 16 + lrow][g * 8];
    const bf16x8 a1 = *(const bf16x8*)&Ts[wave * 16 + lrow][32 + g * 8];
#pragma unroll
    for (int sub = 0; sub < 8; ++sub) {
      const bf16x8 b0 = *(const bf16x8*)&Wsh[sub * 16 + lrow][g * 8];
      const bf16x8 b1 = *(const bf16x8*)&Wsh[sub * 16 + lrow][32 + g * 8];
      f32x4 acc = {0.f, 0.f, 0.f, 0.f};
      acc = __builtin_amdgcn_mfma_f32_16x16x32_bf16(b0, a0, acc, 0, 0, 0);
      acc = __builtin_amdgcn_mfma_f32_16x16x32_bf16(b1, a1, acc, 0, 0, 0);
      const int colg0 = c0 + sub * 16 + g * 4;
      if (colg0 < 1024) {
        const int c2 = colg0 - 512;
        const int hh = c2 >> 6, d0 = c2 & 63;
        u16 o4[4] = {f2bf(acc[0]), f2bf(acc[1]), f2bf(acc[2]), f2bf(acc[3])};
        *(uint2*)&kb[((size_t)hh * NFULL + n) * 64 + d0] = *(const uint2*)o4;
      } else {
        const int c2 = colg0 - 1024;
        const int hh = c2 >> 6, d0 = c2 & 63;
        float4 o4;
        o4.x = acc[0]; o4.y = acc[1]; o4.z = acc[2]; o4.w = acc[3];
        *(float4*)&vh[((size_t)hh * NFULL + n) * 64 + d0] = o4;
      }
    }
  }
}

// K3: attention (frozen structure). Block (h, qt, s): 128 queries, keys
// [s*2048,+2048) in 32 tiles; wave-private global_load_lds staging, 4-deep
// circular swizzled LDS buffer, counted vmcnt, no main-loop barriers.
__global__ __launch_bounds__(256, 2) void k_attn(const u16* __restrict__ qb,
                                                 const u16* __restrict__ kb,
                                                 const float* __restrict__ vh,
                                                 u16* __restrict__ wv16,
                                                 float* __restrict__ dsp) {
  __shared__ __align__(16) u16 KB[4][64][64];
  __shared__ float P_lds[8][16][17];
  __shared__ float Ds[4][8][16];

  const int h = blockIdx.x & 7;
  const int qt = (blockIdx.x >> 3) & 31;
  const int s = blockIdx.x >> 8;
  const int q0 = qt * 128;
  const int tid = threadIdx.x;
  const int wave = tid >> 6, lane = tid & 63;
  const int lrow = lane & 15, g = lane >> 4;

  const u16* __restrict__ Qg = qb + ((size_t)h * NFULL + q0) * 64;
  const u16* __restrict__ Kg = kb + ((size_t)h * NFULL + (size_t)s * 2048) * 64;

  bf16x8 qf[8][2];
#pragma unroll
  for (int j = 0; j < 8; ++j) {
    qf[j][0] = *(const bf16x8*)&Qg[(j * 16 + lrow) * 64 + g * 8];
    qf[j][1] = *(const bf16x8*)&Qg[(j * 16 + lrow) * 64 + 32 + g * 8];
  }

  const int srow8 = lane >> 3;
  const int scol = ((lane & 7) ^ srow8) << 3;

#define STAGE(T, B)                                                           \
  do {                                                                        \
    const u16* tb_ = Kg + (size_t)(T) * 64 * 64;                              \
    {                                                                         \
      const u16* src_ = tb_ + (wave * 16 + srow8) * 64 + scol;                \
      u16* dst_ = &KB[(B)][wave * 16][0];                                     \
      __builtin_amdgcn_global_load_lds(                                       \
          (const __attribute__((address_space(1))) unsigned*)src_,            \
          (__attribute__((address_space(3))) unsigned*)dst_, 16, 0, 0);       \
    }                                                                         \
    {                                                                         \
      const u16* src_ = tb_ + (wave * 16 + 8 + srow8) * 64 + scol;            \
      u16* dst_ = &KB[(B)][wave * 16][0] + 512;                               \
      __builtin_amdgcn_global_load_lds(                                       \
          (const __attribute__((address_space(1))) unsigned*)src_,            \
          (__attribute__((address_space(3))) unsigned*)dst_, 16, 0, 0);       \
    }                                                                         \
  } while (0)

  const int rsw = wave * 16 + lrow;
  const int x0 = (g ^ (lrow & 7)) * 8;
  const int x1 = ((g + 4) ^ (lrow & 7)) * 8;

  float dsum[8];
#pragma unroll
  for (int j = 0; j < 8; ++j) dsum[j] = 0.f;
  const bool dg = (s == (qt >> 4));
  const int ql = qt & 15;

  auto tile = [&](int t, int b) {
    const bf16x8 kf0 = *(const bf16x8*)&KB[b][rsw][x0];
    const bf16x8 kf1 = *(const bf16x8*)&KB[b][rsw][x1];
#pragma unroll
    for (int hs = 0; hs < 2; ++hs) {
      f32x4 a[4];
      __builtin_amdgcn_s_setprio(1);
#pragma unroll
      for (int f = 0; f < 4; ++f) {
        f32x4 t4 = {0.f, 0.f, 0.f, 0.f};
        t4 = __builtin_amdgcn_mfma_f32_16x16x32_bf16(kf0, qf[hs * 4 + f][0], t4, 0, 0, 0);
        t4 = __builtin_amdgcn_mfma_f32_16x16x32_bf16(kf1, qf[hs * 4 + f][1], t4, 0, 0, 0);
        a[f] = t4;
      }
      __builtin_amdgcn_s_setprio(0);
      const bool isd = dg && (t == ql * 2 + hs);
#pragma unroll
      for (int f = 0; f < 4; ++f) {
        const float e0 = EXP2(a[f][0]);
        const float e1 = EXP2(a[f][1]);
        const float e2 = EXP2(a[f][2]);
        const float e3 = EXP2(a[f][3]);
        dsum[hs * 4 + f] += (e0 + e1) + (e2 + e3);
        if (isd && f == wave) {
          const int rr = g * 4;
          const int J = hs * 4 + wave;
          P_lds[J][rr + 0][lrow] = (rr + 0 <= lrow) ? e0 : 0.f;
          P_lds[J][rr + 1][lrow] = (rr + 1 <= lrow) ? e1 : 0.f;
          P_lds[J][rr + 2][lrow] = (rr + 2 <= lrow) ? e2 : 0.f;
          P_lds[J][rr + 3][lrow] = (rr + 3 <= lrow) ? e3 : 0.f;
        }
      }
    }
  };

  STAGE(0, 0); STAGE(1, 1); STAGE(2, 2);

  for (int t = 0; t < 28; t += 2) {
    STAGE(t + 3, (t + 3) & 3);
    asm volatile("s_waitcnt vmcnt(6)" ::: "memory");
    tile(t, t & 3);
    STAGE(t + 4, (t + 4) & 3);
    asm volatile("s_waitcnt vmcnt(6)" ::: "memory");
    tile(t + 1, (t + 1) & 3);
  }
  STAGE(31, 3);
  asm volatile("s_waitcnt vmcnt(6)" ::: "memory");
  tile(28, 0);
  asm volatile("s_waitcnt vmcnt(4)" ::: "memory");
  tile(29, 1);
  asm volatile("s_waitcnt vmcnt(2)" ::: "memory");
  tile(30, 2);
  asm volatile("s_waitcnt vmcnt(0)" ::: "memory");
  tile(31, 3);
#undef STAGE

#pragma unroll
  for (int j = 0; j < 8; ++j) {
    dsum[j] += __shfl_xor(dsum[j], 16);
    dsum[j] += __shfl_xor(dsum[j], 32);
  }
  if (g == 0) {
#pragma unroll
    for (int j = 0; j < 8; ++j) Ds[wave][j][lrow] = dsum[j];
  }
  __syncthreads();

  if (tid < 128) {
    const int J2 = tid >> 4, r = tid & 15;
    const float den = Ds[0][J2][r] + Ds[1][J2][r] + Ds[2][J2][r] + Ds[3][J2][r];
    dsp[((size_t)s * HEADS + h) * NFULL + q0 + J2 * 16 + r] = den;
  }

  if (dg) {
#pragma unroll
    for (int m = 0; m < 2; ++m) {
      const int J = m * 4 + wave;
      const float* __restrict__ V =
          vh + ((size_t)h * NFULL + q0 + J * 16) * 64 + g * 16;
      float o[16];
#pragma unroll
      for (int dd = 0; dd < 16; ++dd) o[dd] = 0.f;
#pragma unroll
      for (int k = 0; k < 16; ++k) {
        const float p = P_lds[J][k][lrow];
        const float4 v0 = *(const float4*)&V[k * 64 + 0];
        const float4 v1 = *(const float4*)&V[k * 64 + 4];
        const float4 v2 = *(const float4*)&V[k * 64 + 8];
        const float4 v3 = *(const float4*)&V[k * 64 + 12];
        o[0] += p * v0.x;  o[1] += p * v0.y;  o[2] += p * v0.z;  o[3] += p * v0.w;
        o[4] += p * v1.x;  o[5] += p * v1.y;  o[6] += p * v1.z;  o[7] += p * v1.w;
        o[8] += p * v2.x;  o[9] += p * v2.y;  o[10] += p * v2.z; o[11] += p * v2.w;
        o[12] += p * v3.x; o[13] += p * v3.y; o[14] += p * v3.z; o[15] += p * v3.w;
      }
      u16 ob[16];
#pragma unroll
      for (int dd = 0; dd < 16; ++dd) ob[dd] = f2bf(o[dd]);
      u16* __restrict__ op =
          wv16 + (size_t)(q0 + J * 16 + lrow) * CDIM + h * 64 + g * 16;
      *(uint4*)&op[0] = *(const uint4*)&ob[0];
      *(uint4*)&op[8] = *(const uint4*)&ob[8];
    }
  }
}

// K4 (fused output): per 16-row block,
// tp[16][32] = norm(wv) @ W_c^T + x @ p_w1^T + bias_c ;  out = tp @ p_w2^T.
__global__ __launch_bounds__(256) void k_out(const u16* __restrict__ wv16,
                                             const float* __restrict__ x,
                                             const float* __restrict__ dsp,
                                             const u16* __restrict__ wcbf,
                                             const u16* __restrict__ pw1bf,
                                             const u16* __restrict__ pw2bf,
                                             const float* __restrict__ bias_c,
                                             float* __restrict__ out) {
  __shared__ __align__(16) u16 wvb[16][520];
  __shared__ __align__(16) u16 xb[16][520];
  __shared__ float tp_part[4][32][17];
  __shared__ float invs[16][8];
  const int r0 = blockIdx.x * 16;
  const int tid = threadIdx.x;
  const int wave = tid >> 6, lane = tid & 63;
  const int lrow = lane & 15, g = lane >> 4;

  if (tid < 128) {
    const int n = tid >> 3, hh = tid & 7;
    const size_t base = (size_t)hh * NFULL + r0 + n;
    invs[n][hh] = 1.0f / (dsp[base] + dsp[(size_t)8 * NFULL + base]);
  }
  __syncthreads();

  for (int rep = 0; rep < 4; ++rep) {
    const int idx = rep * 256 + tid;
    const int row = idx >> 6, c8 = (idx & 63) * 8;
    const float sc = invs[row][c8 >> 6];
    const uint4 wv8 = *(const uint4*)&wv16[(size_t)(r0 + row) * 512 + c8];
    const u16* pw = (const u16*)&wv8;
    u16 t8[8];
#pragma unroll
    for (int i = 0; i < 8; ++i) t8[i] = f2bf(bf2f(pw[i]) * sc);
    *(uint4*)&wvb[row][c8] = *(const uint4*)&t8[0];
    const float4 x0 = *(const float4*)&x[(size_t)(r0 + row) * 512 + c8];
    const float4 x1 = *(const float4*)&x[(size_t)(r0 + row) * 512 + c8 + 4];
    u16 u8[8] = {f2bf(x0.x), f2bf(x0.y), f2bf(x0.z), f2bf(x0.w),
                 f2bf(x1.x), f2bf(x1.y), f2bf(x1.z), f2bf(x1.w)};
    *(uint4*)&xb[row][c8] = *(const uint4*)&u8[0];
  }
  __syncthreads();

  {
    const bool isx = (wave & 2) != 0;
    const int kh = wave & 1;
    const u16* __restrict__ Wsrc = isx ? pw1bf : wcbf;
#pragma unroll
    for (int rt = 0; rt < 2; ++rt) {
      f32x4 acc = {0.f, 0.f, 0.f, 0.f};
#pragma unroll
      for (int ks = 0; ks < 8; ++ks) {
        const int K = kh * 256 + ks * 32 + g * 8;
        const bf16x8 aw = *(const bf16x8*)&Wsrc[(size_t)(rt * 16 + lrow) * 512 + K];
        const bf16x8 bf = isx ? *(const bf16x8*)&xb[lrow][K]
                              : *(const bf16x8*)&wvb[lrow][K];
        acc = __builtin_amdgcn_mfma_f32_16x16x32_bf16(aw, bf, acc, 0, 0, 0);
      }
#pragma unroll
      for (int j = 0; j < 4; ++j)
        tp_part[wave][rt * 16 + g * 4 + j][lrow] = acc[j];
    }
  }
  __syncthreads();

  union { u16 a[8]; bf16x8 v; } bq;
#pragma unroll
  for (int i = 0; i < 8; ++i) {
    const int k = g * 8 + i;
    bq.a[i] = f2bf(tp_part[0][k][lrow] + tp_part[1][k][lrow] +
                   tp_part[2][k][lrow] + tp_part[3][k][lrow] + bias_c[k]);
  }

#pragma unroll
  for (int t = 0; t < 8; ++t) {
    const int ct = wave * 8 + t;
    const bf16x8 aw = *(const bf16x8*)&pw2bf[(size_t)(ct * 16 + lrow) * 32 + g * 8];
    f32x4 acc = {0.f, 0.f, 0.f, 0.f};
    acc = __builtin_amdgcn_mfma_f32_16x16x32_bf16(aw, bq.v, acc, 0, 0, 0);
    float4 res;
    res.x = acc[0]; res.y = acc[1]; res.z = acc[2]; res.w = acc[3];
    *(float4*)&out[(size_t)(r0 + lrow) * 512 + ct * 16 + g * 4] = res;
  }
}

extern "C" void kernel_launch(void* const* d_in, const int* in_sizes, int n_in,
                              void* d_out, int out_size, void* d_ws, size_t ws_size,
                              hipStream_t stream) {
  const float* x     = (const float*)d_in[0];
  const float* q_w1  = (const float*)d_in[1];
  const float* q_w2  = (const float*)d_in[2];
  const float* kv_w1 = (const float*)d_in[3];
  const float* kv_w2 = (const float*)d_in[4];
  const float* dw_w  = (const float*)d_in[5];
  const float* dw_b  = (const float*)d_in[6];
  const float* pw_w  = (const float*)d_in[7];
  const float* pw_b  = (const float*)d_in[8];
  const float* p_w1  = (const float*)d_in[9];
  const float* p_w2  = (const float*)d_in[10];
  float* out = (float*)d_out;

  char* ws = (char*)d_ws;
  float* dsp    = (float*)ws;                        // 2*8*4096 f32 (256KB)
  float* bias2  = (float*)(ws + 262144);             // 512 f32
  float* bias_c = bias2 + 512;                       // 32 f32 (within 4KB pad)
  u16*   wcbf   = (u16*)(ws + 262144 + 4096);        // 32*512 u16 (32KB)
  u16*   pw1bf  = wcbf + 16384;                      // 32KB
  u16*   pw2bf  = pw1bf + 16384;                     // 32KB
  u16*   t_bf   = pw2bf + 16384;                     // 4096*96 u16 (768KB)
  u16*   qbw    = t_bf + (size_t)NFULL * 96;         // 2M u16 (4MB)
  u16*   kbw    = qbw + (size_t)HEADS * NFULL * DDIM;  // 2M u16 (4MB)
  float* vh     = (float*)(kbw + (size_t)HEADS * NFULL * DDIM);  // 2M f32 (8MB)
  u16*   wv16   = (u16*)(vh + (size_t)HEADS * NFULL * DDIM);     // 2M u16 (4MB)

  k_pre<<<202, 256, 0, stream>>>(x, q_w1, kv_w1, t_bf, pw_w, dw_w, dw_b, pw_b,
                                 p_w1, p_w2, bias2, wcbf, pw1bf, pw2bf);
  k_proj2<<<769, 256, 0, stream>>>(t_bf, q_w2, kv_w2, p_w1, bias2, qbw, kbw, vh,
                                   bias_c);
  k_attn<<<2 * HEADS * (NFULL / 128), 256, 0, stream>>>(qbw, kbw, vh, wv16, dsp);
  k_out<<<NFULL / 16, 256, 0, stream>>>(wv16, x, dsp, wcbf, pw1bf, pw2bf, bias_c,
                                        out);
}